// Round 1
// baseline (154.394 us; speedup 1.0000x reference)
//
#include <hip/hip_runtime.h>

typedef __attribute__((ext_vector_type(8))) __bf16 bf16x8;
typedef __attribute__((ext_vector_type(4))) __bf16 bf16x4;
typedef __attribute__((ext_vector_type(4))) float f32x4;

__device__ __forceinline__ void async_load16(const void* g, void* l) {
  __builtin_amdgcn_global_load_lds(
      (const __attribute__((address_space(1))) void*)g,
      (__attribute__((address_space(3))) void*)l, 16, 0, 0);
}

// ---------------- fp32 -> bf16 convert (vectorized) ----------------
__global__ void cvt_f32_bf16(const float* __restrict__ in,
                             __bf16* __restrict__ out, int n4) {
  int i = blockIdx.x * blockDim.x + threadIdx.x;
  int stride = gridDim.x * blockDim.x;
  for (; i < n4; i += stride) {
    float4 v = ((const float4*)in)[i];
    bf16x4 o;
    o[0] = (__bf16)v.x; o[1] = (__bf16)v.y; o[2] = (__bf16)v.z; o[3] = (__bf16)v.w;
    ((bf16x4*)out)[i] = o;
  }
}

// ---------------- C[m][n] = (sum_k A[m][k]*B[n][k] + bias[n]) * scale ----------------
// 128x128 tile, BK=64, 256 threads (4 waves 2x2), global_load_lds staging with
// pre-swizzled source (XOR (row&7)<<4) so ds_read_b128 frag reads are conflict-free.
template <int OUT_BF16>
__global__ __launch_bounds__(256) void gemm_bt(
    const __bf16* __restrict__ A,   // [M][K]
    const __bf16* __restrict__ Bm,  // [N][K]
    const float* __restrict__ bias, // [N]
    void* __restrict__ Cout,
    int M, int N, int K, int qscale_cols) {
  __shared__ __align__(16) char smem[32768];
  char* lA = smem;
  char* lB = smem + 16384;
  const int t = threadIdx.x;
  const int lane = t & 63;
  const int wid = t >> 6;
  const int wm = wid >> 1, wn = wid & 1;
  const int g = lane >> 4, ln = lane & 15;
  const int m0 = blockIdx.y * 128;
  const int n0 = blockIdx.x * 128;

  const int srow = t >> 3;                              // staging row (+32/chunk)
  const int sswz = ((t & 7) * 16) ^ ((srow & 7) << 4);  // pre-swizzled col byte
  const size_t KB = (size_t)K * 2;
  const char* gA = (const char*)A + (size_t)m0 * KB;
  const char* gB = (const char*)Bm + (size_t)n0 * KB;

  f32x4 acc[4][4] = {};

  for (int k0 = 0; k0 < K; k0 += 64) {
    __syncthreads();
#pragma unroll
    for (int c = 0; c < 4; ++c) {
      int row = srow + 32 * c;  // (row&7)==(srow&7)
      async_load16(gA + (size_t)row * KB + k0 * 2 + sswz, lA + c * 4096 + t * 16);
      async_load16(gB + (size_t)row * KB + k0 * 2 + sswz, lB + c * 4096 + t * 16);
    }
    __syncthreads();
#pragma unroll
    for (int ks = 0; ks < 2; ++ks) {
      bf16x8 af[4], bf[4];
#pragma unroll
      for (int i = 0; i < 4; ++i) {
        int ar = wm * 64 + i * 16 + ln;
        int byo = (ks * 64 + g * 16) ^ ((ar & 7) << 4);
        af[i] = *(const bf16x8*)(lA + ar * 128 + byo);
        int br = wn * 64 + i * 16 + ln;
        bf[i] = *(const bf16x8*)(lB + br * 128 + byo);
      }
#pragma unroll
      for (int i = 0; i < 4; ++i)
#pragma unroll
        for (int j = 0; j < 4; ++j)
          acc[i][j] = __builtin_amdgcn_mfma_f32_16x16x32_bf16(af[i], bf[j], acc[i][j], 0, 0, 0);
    }
  }

  // epilogue: D row = 4*(lane>>4)+reg (+16*i), col = lane&15 (+16*j)
#pragma unroll
  for (int j = 0; j < 4; ++j) {
    int col = n0 + wn * 64 + j * 16 + ln;
    float bv = bias[col];
    float scale = (col < qscale_cols) ? 0.125f : 1.0f;
#pragma unroll
    for (int i = 0; i < 4; ++i) {
      int row0 = m0 + wm * 64 + i * 16 + g * 4;
#pragma unroll
      for (int r = 0; r < 4; ++r) {
        float v = (acc[i][j][r] + bv) * scale;
        if (OUT_BF16)
          ((__bf16*)Cout)[(size_t)(row0 + r) * N + col] = (__bf16)v;
        else
          ((float*)Cout)[(size_t)(row0 + r) * N + col] = v;
      }
    }
  }
}

// ---------------- fused flash attention ----------------
// grid (32 q-tiles, 8 batches), 512 threads = 8 waves, wave h = head h.
// QT=32 rows/block, KT=64. Bias tile shared across heads via LDS.
__global__ __launch_bounds__(512) void attn_fused(
    const __bf16* __restrict__ qkv,  // [B][N][1536], q cols pre-scaled by 1/8
    const float* __restrict__ gbias, // [B][N][N]
    const float* __restrict__ bstr,  // [1]
    __bf16* __restrict__ attn) {     // [B][N][512]
  __shared__ __align__(16) char smem[8 * 16384 + 32 * 65 * 4];
  const int t = threadIdx.x;
  const int lane = t & 63;
  const int h = t >> 6;
  const int g = lane >> 4, ln = lane & 15;
  const int b = blockIdx.y;
  const int q0 = blockIdx.x * 32;

  char* Ks = smem + h * 16384;  // [64 k][128B], XOR-swizzled via source
  char* Ps = Ks;                // alias: P[32 q][128B] overwrites K after QK^T
  char* Vs = Ks + 8192;         // [64 k][128B], linear
  float* bias_s = (float*)(smem + 8 * 16384);  // [32 q][65 f32]

  const float alpha = 1.f / (1.f + __expf(-bstr[0]));
  const float bscale = 10.f * alpha;
  const f32x4 fzero = {0.f, 0.f, 0.f, 0.f};

  // Q fragments (A-operand: row = ln (+16*mi), k = 8*g+i (+32*ks)), pre-scaled by 1/8
  bf16x8 qf[2][2];
#pragma unroll
  for (int mi = 0; mi < 2; ++mi)
#pragma unroll
    for (int ks = 0; ks < 2; ++ks) {
      const char* src = (const char*)qkv +
          (((size_t)b * 1024 + q0 + mi * 16 + ln) * 1536 + h * 64 + ks * 32 + g * 8) * 2;
      qf[mi][ks] = *(const bf16x8*)src;
    }

  float m_run[2][4], l_run[2][4];
  f32x4 o_acc[2][4] = {};
#pragma unroll
  for (int mi = 0; mi < 2; ++mi)
#pragma unroll
    for (int r = 0; r < 4; ++r) { m_run[mi][r] = -1e30f; l_run[mi][r] = 0.f; }

  const int krow0 = lane >> 3;
  const int kcb = (lane & 7) * 16;

  for (int kt = 0; kt < 16; ++kt) {
    const int k0 = kt * 64;
    __syncthreads();  // previous iteration's bias/P reads complete
    // bias_s[q][k] = 10*alpha*(sigmoid(gbias[b][k0+k][q0+q]) - 0.5)   (transposed read)
    {
      int gk = t >> 3, q4 = (t & 7) * 4;
      float4 v = *(const float4*)(gbias + ((size_t)b * 1024 + k0 + gk) * 1024 + q0 + q4);
      float vv[4] = {v.x, v.y, v.z, v.w};
#pragma unroll
      for (int j = 0; j < 4; ++j) {
        float sgm = 1.f / (1.f + __expf(-vv[j]));
        bias_s[(q4 + j) * 65 + gk] = bscale * (sgm - 0.5f);
      }
    }
    // K (swizzled source) and V (linear) staged per wave, async
#pragma unroll
    for (int c = 0; c < 8; ++c) {
      int row = c * 8 + krow0;  // (row&7)==(krow0&7)... krow0 in [0,8): row&7==krow0... careful: c*8 keeps &7
      const char* base = (const char*)qkv + ((size_t)b * 1024 + k0 + row) * 3072;
      async_load16(base + (512 + h * 64) * 2 + (kcb ^ ((row & 7) << 4)), Ks + c * 1024 + lane * 16);
      async_load16(base + (1024 + h * 64) * 2 + kcb, Vs + c * 1024 + lane * 16);
    }
    __syncthreads();  // drains vmcnt: bias + K + V visible

    // S = Q K^T + bias    (D layout: q = mi*16 + 4g + r, k = ni*16 + ln)
    f32x4 s[2][4];
#pragma unroll
    for (int ni = 0; ni < 4; ++ni) {
      int br = ni * 16 + ln;
      int sw = (br & 7) << 4;
#pragma unroll
      for (int ks = 0; ks < 2; ++ks) {
        bf16x8 kf = *(const bf16x8*)(Ks + br * 128 + ((ks * 64 + g * 16) ^ sw));
#pragma unroll
        for (int mi = 0; mi < 2; ++mi)
          s[mi][ni] = __builtin_amdgcn_mfma_f32_16x16x32_bf16(
              qf[mi][ks], kf, (ks == 0) ? fzero : s[mi][ni], 0, 0, 0);
      }
#pragma unroll
      for (int mi = 0; mi < 2; ++mi)
#pragma unroll
        for (int r = 0; r < 4; ++r)
          s[mi][ni][r] += bias_s[(mi * 16 + g * 4 + r) * 65 + ni * 16 + ln];
    }

    // online softmax over k; row stats reduced across the 16-lane group
#pragma unroll
    for (int mi = 0; mi < 2; ++mi)
#pragma unroll
      for (int r = 0; r < 4; ++r) {
        float tm = fmaxf(fmaxf(s[mi][0][r], s[mi][1][r]), fmaxf(s[mi][2][r], s[mi][3][r]));
#pragma unroll
        for (int off = 1; off < 16; off <<= 1)
          tm = fmaxf(tm, __shfl_xor(tm, off, 64));
        float newm = fmaxf(m_run[mi][r], tm);
        float corr = __expf(m_run[mi][r] - newm);
        float rs = 0.f;
#pragma unroll
        for (int ni = 0; ni < 4; ++ni) {
          float p = __expf(s[mi][ni][r] - newm);
          s[mi][ni][r] = p;
          rs += p;
        }
#pragma unroll
        for (int off = 1; off < 16; off <<= 1)
          rs += __shfl_xor(rs, off, 64);
        m_run[mi][r] = newm;
        l_run[mi][r] = l_run[mi][r] * corr + rs;
#pragma unroll
        for (int di = 0; di < 4; ++di)
          o_acc[mi][di][r] *= corr;
      }

    // P -> LDS (bf16, XOR-swizzled), overwrites K region (K reads are done)
#pragma unroll
    for (int mi = 0; mi < 2; ++mi)
#pragma unroll
      for (int ni = 0; ni < 4; ++ni)
#pragma unroll
        for (int r = 0; r < 4; ++r) {
          int q = mi * 16 + g * 4 + r;
          int cb = (ni * 16 + ln) * 2;
          *(__bf16*)(Ps + q * 128 + (cb ^ ((q & 7) << 4))) = (__bf16)s[mi][ni][r];
        }

    // O += P V   (A-frag from Ps via b128; V B-frag gathered elementwise)
#pragma unroll
    for (int ks = 0; ks < 2; ++ks) {
      bf16x8 pf[2];
#pragma unroll
      for (int mi = 0; mi < 2; ++mi) {
        int q = mi * 16 + ln;
        pf[mi] = *(const bf16x8*)(Ps + q * 128 + ((ks * 64 + g * 16) ^ ((q & 7) << 4)));
      }
#pragma unroll
      for (int di = 0; di < 4; ++di) {
        bf16x8 vf;
#pragma unroll
        for (int i = 0; i < 8; ++i)
          vf[i] = *(const __bf16*)(Vs + (ks * 32 + g * 8 + i) * 128 + (di * 16 + ln) * 2);
#pragma unroll
        for (int mi = 0; mi < 2; ++mi)
          o_acc[mi][di] = __builtin_amdgcn_mfma_f32_16x16x32_bf16(pf[mi], vf, o_acc[mi][di], 0, 0, 0);
      }
    }
  }

  // normalize + store bf16 (attn[b][q][h*64+d])
#pragma unroll
  for (int mi = 0; mi < 2; ++mi)
#pragma unroll
    for (int r = 0; r < 4; ++r) {
      float inv = 1.f / l_run[mi][r];
      int q = q0 + mi * 16 + g * 4 + r;
#pragma unroll
      for (int di = 0; di < 4; ++di) {
        int d = h * 64 + di * 16 + ln;
        attn[((size_t)b * 1024 + q) * 512 + d] = (__bf16)(o_acc[mi][di][r] * inv);
      }
    }
}

extern "C" void kernel_launch(void* const* d_in, const int* in_sizes, int n_in,
                              void* d_out, int out_size, void* d_ws, size_t ws_size,
                              hipStream_t stream) {
  const float* x     = (const float*)d_in[0];
  const float* gb    = (const float*)d_in[1];
  const float* w_in  = (const float*)d_in[2];
  const float* b_in  = (const float*)d_in[3];
  const float* w_out = (const float*)d_in[4];
  const float* b_out = (const float*)d_in[5];
  const float* bstr  = (const float*)d_in[6];

  char* ws = (char*)d_ws;
  __bf16* qkv = (__bf16*)(ws);                                  // 8*1024*1536*2 = 25165824 B
  __bf16* xb  = (__bf16*)(ws + 25165824);                       // 8*1024*512*2 = 8388608 B
  __bf16* w1  = (__bf16*)(ws + 25165824 + 8388608);             // 1536*512*2 = 1572864 B
  __bf16* w2  = (__bf16*)(ws + 25165824 + 8388608 + 1572864);   // 512*512*2 = 524288 B
  __bf16* attn_buf = xb;  // alias: x_bf16 dead after GEMM1

  cvt_f32_bf16<<<2048, 256, 0, stream>>>(x, xb, (8 * 1024 * 512) / 4);
  cvt_f32_bf16<<<768, 256, 0, stream>>>(w_in, w1, (1536 * 512) / 4);
  cvt_f32_bf16<<<256, 256, 0, stream>>>(w_out, w2, (512 * 512) / 4);

  // qkv = x @ W_in^T + b_in, q columns (<512) scaled by 1/sqrt(64)=0.125, bf16 out
  gemm_bt<1><<<dim3(12, 64), 256, 0, stream>>>(xb, w1, b_in, qkv, 8192, 1536, 512, 512);
  // fused attention -> attn_buf (bf16, [B][N][512])
  attn_fused<<<dim3(32, 8), 512, 0, stream>>>(qkv, gb, bstr, attn_buf);
  // out = attn @ W_out^T + b_out, fp32
  gemm_bt<0><<<dim3(4, 64), 256, 0, stream>>>(attn_buf, w2, b_out, d_out, 8192, 512, 512, 0);
}